// Round 1
// baseline (3091.219 us; speedup 1.0000x reference)
//
#include <hip/hip_runtime.h>
#include <hip/hip_cooperative_groups.h>
#include <math.h>

namespace cg = cooperative_groups;

#define H    1024
#define C    151
#define E    200
#define DIN  2048
#define T    32
#define B    128
#define SIXH  (6*H)   // 6144
#define FIVEH (5*H)   // 5120
#define KTOT  DIN     // 2048
#define NEMB  (C+1)   // 152
#define NWG   160     // persistent blocks; 160*32 = 5120 cols
#define COLS  32      // ps columns per WG

typedef _Float16 f16x8 __attribute__((ext_vector_type(8)));
typedef _Float16 f16x4 __attribute__((ext_vector_type(4)));
typedef float    f32x4 __attribute__((ext_vector_type(4)));

#define GLOAD_LDS16(g, l) __builtin_amdgcn_global_load_lds( \
    (const __attribute__((address_space(1))) unsigned int*)(g), \
    (__attribute__((address_space(3))) unsigned int*)(l), 16, 0, 0)

// ---------------- init: zero h, c, hhi, hlo, eidx ----------------
__global__ void init_kernel(float* h, float* c, _Float16* hhi, _Float16* hlo, int* eidx) {
    int i = blockIdx.x * blockDim.x + threadIdx.x;
    if (i < B * H) {
        h[i] = 0.f; c[i] = 0.f;
        hhi[i] = (_Float16)0.f; hlo[i] = (_Float16)0.f;
    }
    if (i < B) eidx[i] = 0;
}

// ---------------- X [4096][2048] fp32 -> hi/lo fp16 (same layout) ----------------
__global__ void cvt_x(const float* __restrict__ X, _Float16* __restrict__ hi,
                      _Float16* __restrict__ lo) {
    size_t i = ((size_t)blockIdx.x * 256 + threadIdx.x) * 4;
    float4 v = *(const float4*)(X + i);
    f16x4 h, l;
    h.x = (_Float16)v.x; l.x = (_Float16)(v.x - (float)h.x);
    h.y = (_Float16)v.y; l.y = (_Float16)(v.y - (float)h.y);
    h.z = (_Float16)v.z; l.z = (_Float16)(v.z - (float)h.z);
    h.w = (_Float16)v.w; l.w = (_Float16)(v.w - (float)h.w);
    *(f16x4*)(hi + i) = h;
    *(f16x4*)(lo + i) = l;
}

// ---------------- W [KR][NC] fp32 -> out [NC][KR] hi/lo fp16 (transposed) ----------------
template<int KR, int NC>
__global__ void cvt_wT(const float* __restrict__ W, _Float16* __restrict__ hi,
                       _Float16* __restrict__ lo) {
    __shared__ float tile[32][33];
    int n0 = blockIdx.x * 32, k0 = blockIdx.y * 32;
    int tx = threadIdx.x & 31, ty = threadIdx.x >> 5;   // ty 0..7
    #pragma unroll
    for (int i = 0; i < 4; ++i) {
        int k = ty + i * 8;
        tile[k][tx] = W[(size_t)(k0 + k) * NC + n0 + tx];
    }
    __syncthreads();
    #pragma unroll
    for (int i = 0; i < 4; ++i) {
        int n = ty + i * 8;
        float v = tile[tx][n];              // = W[k0+tx][n0+n]
        _Float16 h = (_Float16)v;
        size_t o = (size_t)(n0 + n) * KR + k0 + tx;
        hi[o] = h;
        lo[o] = (_Float16)(v - (float)h);
    }
}

// ---------------- Wo [H][C] fp32 -> WoT [C][H] ----------------
__global__ void cvt_woT(const float* __restrict__ Wo, float* __restrict__ WoT) {
    int k = blockIdx.x * 256 + threadIdx.x;  // 0..H-1
    for (int c = 0; c < C; ++c)
        WoT[(size_t)c * H + k] = Wo[(size_t)k * C + c];
}

// ---------------- Etab[k][n] = sum_e embed[k][e] * Wi[DIN+e][n]  (fp32) ----------------
__global__ void etab_kernel(const float* __restrict__ embed,
                            const float* __restrict__ Wi,
                            float* __restrict__ Etab) {
    int n = blockIdx.x * 256 + threadIdx.x;
    int k = blockIdx.y;
    const float* wp = Wi + (size_t)DIN * SIXH + n;
    const float* ep = embed + k * E;
    float acc = 0.f;
    #pragma unroll 8
    for (int e = 0; e < E; ++e)
        acc = fmaf(ep[e], wp[(size_t)e * SIXH], acc);
    Etab[(size_t)k * SIXH + n] = acc;
}

// ---------------- P = X @ Wi_x + bi, fp16x3 MFMA. tile 128x128, 4 waves x 64x64 ----------
// A = Xhi/Xlo [4096][2048] (k-contig). B = WiT hi/lo [6144][2048] (k-contig).
// LDS slot swizzle (T2 both-sides): source chunk kc ^ ((row>>1)&3), read slot lq ^ ((lr>>1)&3).
__global__ __launch_bounds__(256) void big_gemm_mfma(
    const _Float16* __restrict__ Ahi, const _Float16* __restrict__ Alo,
    const _Float16* __restrict__ Bhi, const _Float16* __restrict__ Blo,
    const float* __restrict__ bi, float* __restrict__ P)
{
    __shared__ __align__(16) _Float16 sAh[128 * 32];
    __shared__ __align__(16) _Float16 sAl[128 * 32];
    __shared__ __align__(16) _Float16 sBh[128 * 32];
    __shared__ __align__(16) _Float16 sBl[128 * 32];
    const int tid = threadIdx.x;
    const int n0 = blockIdx.x * 128;
    const int m0 = blockIdx.y * 128;
    const int lane = tid & 63, w = tid >> 6;
    const int wm = (w >> 1) * 64, wn = (w & 1) * 64;
    const int lr = lane & 15, lq = lane >> 4;

    f32x4 acc[4][4];
    #pragma unroll
    for (int i = 0; i < 4; ++i)
        #pragma unroll
        for (int j = 0; j < 4; ++j)
            acc[i][j] = (f32x4){0.f, 0.f, 0.f, 0.f};

    const int row0 = tid >> 2;        // 0..63
    const int kc = tid & 3;
    const int kcs = kc ^ ((row0 >> 1) & 3);   // swizzled source chunk
    const int sw = (lq ^ ((lr >> 1) & 3)) * 8; // swizzled read slot (halves)

    for (int k0 = 0; k0 < KTOT; k0 += 32) {
        #pragma unroll
        for (int i = 0; i < 2; ++i) {
            int row = row0 + i * 64;
            size_t ga = (size_t)(m0 + row) * KTOT + k0 + kcs * 8;
            size_t gb = (size_t)(n0 + row) * KTOT + k0 + kcs * 8;
            int loff = (i * 256 + tid) * 8;        // halves (linear dest)
            GLOAD_LDS16(Ahi + ga, sAh + loff);
            GLOAD_LDS16(Alo + ga, sAl + loff);
            GLOAD_LDS16(Bhi + gb, sBh + loff);
            GLOAD_LDS16(Blo + gb, sBl + loff);
        }
        __syncthreads();
        f16x8 ah[4], al[4], bh[4], bl[4];
        #pragma unroll
        for (int i = 0; i < 4; ++i) {
            ah[i] = *(const f16x8*)&sAh[(wm + i * 16 + lr) * 32 + sw];
            al[i] = *(const f16x8*)&sAl[(wm + i * 16 + lr) * 32 + sw];
            bh[i] = *(const f16x8*)&sBh[(wn + i * 16 + lr) * 32 + sw];
            bl[i] = *(const f16x8*)&sBl[(wn + i * 16 + lr) * 32 + sw];
        }
        #pragma unroll
        for (int i = 0; i < 4; ++i)
            #pragma unroll
            for (int j = 0; j < 4; ++j) {
                acc[i][j] = __builtin_amdgcn_mfma_f32_16x16x32_f16(ah[i], bh[j], acc[i][j], 0, 0, 0);
                acc[i][j] = __builtin_amdgcn_mfma_f32_16x16x32_f16(ah[i], bl[j], acc[i][j], 0, 0, 0);
                acc[i][j] = __builtin_amdgcn_mfma_f32_16x16x32_f16(al[i], bh[j], acc[i][j], 0, 0, 0);
            }
        __syncthreads();
    }
    #pragma unroll
    for (int i = 0; i < 4; ++i)
        #pragma unroll
        for (int j = 0; j < 4; ++j) {
            int gcol = n0 + wn + j * 16 + lr;
            float bv = bi[gcol];
            #pragma unroll
            for (int r = 0; r < 4; ++r) {
                int grow = m0 + wm + i * 16 + lq * 4 + r;
                P[(size_t)grow * SIXH + gcol] = acc[i][j][r] + bv;
            }
        }
}

// ================= persistent fused timestep loop (cooperative) =================
// Grid = NWG(160) x 256. Ws-slice (32 cols x 1024 k, hi+lo fp16) resident in LDS,
// loaded ONCE. Per step: phase1 ps-slice (no barriers in K-loop), grid.sync,
// phase2 (wg<128 => b=wg): gate (c in regs, eidx in LDS) + pred + argmax, grid.sync.
__global__ __launch_bounds__(256) void fused_loop(
    const float* __restrict__ P,
    const float* __restrict__ Etab,
    const float* __restrict__ bs,
    const _Float16* __restrict__ WsThi,
    const _Float16* __restrict__ WsTlo,
    _Float16* __restrict__ hhi,
    _Float16* __restrict__ hlo,
    float* __restrict__ ps,
    const float* __restrict__ WoT,
    const float* __restrict__ bo,
    const int* __restrict__ labels,
    float* __restrict__ dists,
    float* __restrict__ comms)
{
    __shared__ __align__(16) _Float16 sBh[COLS * H];   // 64 KB, XOR-swizzled
    __shared__ __align__(16) _Float16 sBl[COLS * H];   // 64 KB
    __shared__ __align__(16) float hs[H];              // 4 KB (h_new row for pred)
    __shared__ float vals[256];
    __shared__ int   idxs[256];
    __shared__ int   s_eidx;

    cg::grid_group grid = cg::this_grid();
    const int wg  = blockIdx.x;
    const int tid = threadIdx.x;
    const int n0  = wg * COLS;
    const int lane = tid & 63, w = tid >> 6;
    const int lr = lane & 15, lq = lane >> 4;

    // ---- stage Ws slice into LDS, swizzled: granule g' = g ^ (col&7) ----
    for (int gi = tid; gi < COLS * (H / 8); gi += 256) {
        int col = gi >> 7;          // 128 granules of 16B per col
        int kg  = gi & 127;
        int dst = (col * (H * 2) + kg * 16) ^ ((col & 7) << 4);   // bytes
        *(f16x8*)((char*)sBh + dst) = *(const f16x8*)&WsThi[(size_t)(n0 + col) * H + kg * 8];
        *(f16x8*)((char*)sBl + dst) = *(const f16x8*)&WsTlo[(size_t)(n0 + col) * H + kg * 8];
    }

    float creg[4] = {0.f, 0.f, 0.f, 0.f};   // c-state, j = jj*256 + tid
    float bsr[4][5];
    if (wg < B) {
        #pragma unroll
        for (int jj = 0; jj < 4; ++jj)
            #pragma unroll
            for (int k = 0; k < 5; ++k)
                bsr[jj][k] = bs[k * H + jj * 256 + tid];
    }
    if (tid == 0) s_eidx = 0;
    grid.sync();

    const int mrow0 = w * 32;

    for (int t = 0; t < T; ++t) {
        // ---------- phase 1: ps[:, n0:n0+32] = (h) @ Ws-slice, fp16x3 ----------
        f32x4 acc[2][2];
        #pragma unroll
        for (int i = 0; i < 2; ++i)
            #pragma unroll
            for (int j = 0; j < 2; ++j)
                acc[i][j] = (f32x4){0.f, 0.f, 0.f, 0.f};

        #pragma unroll 2
        for (int k0 = 0; k0 < H; k0 += 32) {
            f16x8 ah[2], al[2], bh[2], bl[2];
            #pragma unroll
            for (int i = 0; i < 2; ++i) {
                size_t ho = (size_t)(mrow0 + i * 16 + lr) * H + k0 + lq * 8;
                ah[i] = *(const f16x8*)&hhi[ho];
                al[i] = *(const f16x8*)&hlo[ho];
            }
            #pragma unroll
            for (int j = 0; j < 2; ++j) {
                int col = j * 16 + lr;
                int off = (col * (H * 2) + (k0 + lq * 8) * 2) ^ ((col & 7) << 4);
                bh[j] = *(const f16x8*)((const char*)sBh + off);
                bl[j] = *(const f16x8*)((const char*)sBl + off);
            }
            #pragma unroll
            for (int i = 0; i < 2; ++i)
                #pragma unroll
                for (int j = 0; j < 2; ++j) {
                    acc[i][j] = __builtin_amdgcn_mfma_f32_16x16x32_f16(ah[i], bh[j], acc[i][j], 0, 0, 0);
                    acc[i][j] = __builtin_amdgcn_mfma_f32_16x16x32_f16(ah[i], bl[j], acc[i][j], 0, 0, 0);
                    acc[i][j] = __builtin_amdgcn_mfma_f32_16x16x32_f16(al[i], bh[j], acc[i][j], 0, 0, 0);
                }
        }
        #pragma unroll
        for (int i = 0; i < 2; ++i)
            #pragma unroll
            for (int j = 0; j < 2; ++j)
                #pragma unroll
                for (int r = 0; r < 4; ++r)
                    ps[(size_t)(mrow0 + i * 16 + lq * 4 + r) * FIVEH + n0 + j * 16 + lr] = acc[i][j][r];

        grid.sync();

        // ---------- phase 2: gate + pred + argmax for b = wg ----------
        if (wg < B) {
            const int b = wg;
            const float* prow = P + (size_t)(t * B + b) * SIXH;
            const float* erow = Etab + (size_t)s_eidx * SIXH;
            const float* psr  = ps + (size_t)b * FIVEH;
            #pragma unroll
            for (int jj = 0; jj < 4; ++jj) {
                int j = jj * 256 + tid;
                float gv[5];
                #pragma unroll
                for (int k = 0; k < 5; ++k) {
                    int col = k * H + j;
                    gv[k] = prow[col] + erow[col] + psr[col] + bsr[jj][k];
                }
                float pi5 = prow[5 * H + j] + erow[5 * H + j];
                float ig = 1.f / (1.f + expf(-gv[0]));
                float fg = 1.f / (1.f + expf(-gv[1]));
                float mi = tanhf(gv[2]);
                float og = 1.f / (1.f + expf(-gv[3]));
                float hw = 1.f / (1.f + expf(-gv[4]));
                float cn = ig * mi + fg * creg[jj];
                float out = og * tanhf(cn);
                float hn = hw * out + (1.f - hw) * pi5;
                creg[jj] = cn;
                hs[j] = hn;
                _Float16 hh = (_Float16)hn;
                hhi[(size_t)b * H + j] = hh;
                hlo[(size_t)b * H + j] = (_Float16)(hn - (float)hh);
            }
            __syncthreads();
            float predv = 0.f;
            if (tid < C) {
                const float* wp = WoT + (size_t)tid * H;
                float a0 = bo[tid], a1 = 0.f, a2 = 0.f, a3 = 0.f;
                #pragma unroll 4
                for (int k = 0; k < H; k += 4) {
                    float4 w4 = *(const float4*)&wp[k];
                    float4 h4 = *(const float4*)&hs[k];
                    a0 = fmaf(h4.x, w4.x, a0);
                    a1 = fmaf(h4.y, w4.y, a1);
                    a2 = fmaf(h4.z, w4.z, a2);
                    a3 = fmaf(h4.w, w4.w, a3);
                }
                predv = (a0 + a1) + (a2 + a3);
                dists[(size_t)(t * B + b) * C + tid] = predv;
            }
            vals[tid] = (tid >= 1 && tid < C) ? predv : -1e30f;
            idxs[tid] = tid;
            __syncthreads();
            for (int s = 128; s > 0; s >>= 1) {
                if (tid < s) {
                    float v2 = vals[tid + s];
                    int   i2 = idxs[tid + s];
                    if (v2 > vals[tid] || (v2 == vals[tid] && i2 < idxs[tid])) {
                        vals[tid] = v2;
                        idxs[tid] = i2;
                    }
                }
                __syncthreads();
            }
            if (tid == 0) {
                int nzp = idxs[0];
                int lt = labels[t * B + b];
                int comm = (lt == 0) ? nzp : lt;
                comms[t * B + b] = (float)comm;
                s_eidx = comm + 1;
            }
        }
        grid.sync();
    }
}

// ================= fallback per-timestep kernels (used only if coop launch fails) =====
__global__ __launch_bounds__(256) void ps_mfma(
    const _Float16* __restrict__ Ahi, const _Float16* __restrict__ Alo,
    const _Float16* __restrict__ Bhi, const _Float16* __restrict__ Blo,
    float* __restrict__ ps)
{
    __shared__ __align__(16) _Float16 sAh[64 * 32];
    __shared__ __align__(16) _Float16 sAl[64 * 32];
    __shared__ __align__(16) _Float16 sBh[64 * 32];
    __shared__ __align__(16) _Float16 sBl[64 * 32];
    const int tid = threadIdx.x;
    const int n0 = blockIdx.x * 64;
    const int m0 = blockIdx.y * 64;
    const int lane = tid & 63, w = tid >> 6;
    const int wm = (w >> 1) * 32, wn = (w & 1) * 32;
    const int lr = lane & 15, lq = lane >> 4;

    f32x4 acc[2][2];
    #pragma unroll
    for (int i = 0; i < 2; ++i)
        #pragma unroll
        for (int j = 0; j < 2; ++j)
            acc[i][j] = (f32x4){0.f, 0.f, 0.f, 0.f};

    const int row = tid >> 2;
    const int kc = tid & 3;

    for (int k0 = 0; k0 < H; k0 += 32) {
        size_t ga = (size_t)(m0 + row) * H + k0 + kc * 8;
        size_t gb = (size_t)(n0 + row) * H + k0 + kc * 8;
        int loff = tid * 8;
        GLOAD_LDS16(Ahi + ga, sAh + loff);
        GLOAD_LDS16(Alo + ga, sAl + loff);
        GLOAD_LDS16(Bhi + gb, sBh + loff);
        GLOAD_LDS16(Blo + gb, sBl + loff);
        __syncthreads();
        f16x8 ah[2], al[2], bh[2], bl[2];
        #pragma unroll
        for (int i = 0; i < 2; ++i) {
            ah[i] = *(const f16x8*)&sAh[(wm + i * 16 + lr) * 32 + lq * 8];
            al[i] = *(const f16x8*)&sAl[(wm + i * 16 + lr) * 32 + lq * 8];
            bh[i] = *(const f16x8*)&sBh[(wn + i * 16 + lr) * 32 + lq * 8];
            bl[i] = *(const f16x8*)&sBl[(wn + i * 16 + lr) * 32 + lq * 8];
        }
        #pragma unroll
        for (int i = 0; i < 2; ++i)
            #pragma unroll
            for (int j = 0; j < 2; ++j) {
                acc[i][j] = __builtin_amdgcn_mfma_f32_16x16x32_f16(ah[i], bh[j], acc[i][j], 0, 0, 0);
                acc[i][j] = __builtin_amdgcn_mfma_f32_16x16x32_f16(ah[i], bl[j], acc[i][j], 0, 0, 0);
                acc[i][j] = __builtin_amdgcn_mfma_f32_16x16x32_f16(al[i], bh[j], acc[i][j], 0, 0, 0);
            }
        __syncthreads();
    }
    #pragma unroll
    for (int i = 0; i < 2; ++i)
        #pragma unroll
        for (int j = 0; j < 2; ++j) {
            int gcol = n0 + wn + j * 16 + lr;
            #pragma unroll
            for (int r = 0; r < 4; ++r) {
                int grow = m0 + wm + i * 16 + lq * 4 + r;
                ps[(size_t)grow * FIVEH + gcol] = acc[i][j][r];
            }
        }
}

__global__ void gate_kernel(const float* __restrict__ P,
                            const float* __restrict__ Etab,
                            const float* __restrict__ ps,
                            const float* __restrict__ bs,
                            const int* __restrict__ eidx,
                            float* __restrict__ h,
                            float* __restrict__ c,
                            _Float16* __restrict__ hhi,
                            _Float16* __restrict__ hlo,
                            int t) {
    int j = blockIdx.x * 256 + threadIdx.x;
    int b = blockIdx.y;
    const float* prow = P + (size_t)(t * B + b) * SIXH;
    const float* erow = Etab + (size_t)eidx[b] * SIXH;
    const float* psr  = ps + (size_t)b * FIVEH;
    float g[5];
    #pragma unroll
    for (int k = 0; k < 5; ++k) {
        int col = k * H + j;
        g[k] = prow[col] + erow[col] + psr[col] + bs[col];
    }
    float pi5 = prow[5 * H + j] + erow[5 * H + j];
    float ig = 1.f / (1.f + expf(-g[0]));
    float fg = 1.f / (1.f + expf(-g[1]));
    float mi = tanhf(g[2]);
    float og = 1.f / (1.f + expf(-g[3]));
    float hw = 1.f / (1.f + expf(-g[4]));
    float cv = c[b * H + j];
    float cn = ig * mi + fg * cv;
    float out = og * tanhf(cn);
    float hn = hw * out + (1.f - hw) * pi5;
    c[b * H + j] = cn;
    h[b * H + j] = hn;
    _Float16 hh = (_Float16)hn;
    hhi[b * H + j] = hh;
    hlo[b * H + j] = (_Float16)(hn - (float)hh);
}

__global__ void pred_kernel(const float* __restrict__ h,
                            const float* __restrict__ Wo,
                            const float* __restrict__ bo,
                            const int* __restrict__ labels,
                            float* __restrict__ dists,
                            float* __restrict__ comms,
                            int* __restrict__ eidx,
                            int t) {
    __shared__ float hsb[H];
    __shared__ float vals[256];
    __shared__ int   idxs[256];
    int tid = threadIdx.x;
    int b = blockIdx.x;
    for (int i = tid; i < H / 4; i += 256)
        *(float4*)&hsb[i * 4] = *(const float4*)&h[b * H + i * 4];
    __syncthreads();
    float pred = 0.f;
    if (tid < C) {
        pred = bo[tid];
        #pragma unroll 8
        for (int k = 0; k < H; ++k)
            pred = fmaf(hsb[k], Wo[k * C + tid], pred);
        dists[(size_t)(t * B + b) * C + tid] = pred;
    }
    vals[tid] = (tid >= 1 && tid < C) ? pred : -1e30f;
    idxs[tid] = tid;
    __syncthreads();
    for (int s = 128; s > 0; s >>= 1) {
        if (tid < s) {
            float v2 = vals[tid + s];
            int   i2 = idxs[tid + s];
            if (v2 > vals[tid] || (v2 == vals[tid] && i2 < idxs[tid])) {
                vals[tid] = v2;
                idxs[tid] = i2;
            }
        }
        __syncthreads();
    }
    if (tid == 0) {
        int nzp = idxs[0];
        int lt = labels[t * B + b];
        int comm = (lt == 0) ? nzp : lt;
        comms[t * B + b] = (float)comm;
        eidx[b] = comm + 1;
    }
}

extern "C" void kernel_launch(void* const* d_in, const int* in_sizes, int n_in,
                              void* d_out, int out_size, void* d_ws, size_t ws_size,
                              hipStream_t stream) {
    const float* X      = (const float*)d_in[0];
    const int*   labels = (const int*)  d_in[1];
    const float* embed  = (const float*)d_in[2];
    const float* Wi     = (const float*)d_in[3];
    const float* bi     = (const float*)d_in[4];
    const float* Ws     = (const float*)d_in[5];
    const float* bs     = (const float*)d_in[6];
    const float* Wo     = (const float*)d_in[7];
    const float* bo     = (const float*)d_in[8];

    char* w = (char*)d_ws;
    float* P      = (float*)w;              w += (size_t)T * B * SIXH * 4;      // 100.7 MB
    float* Etab   = (float*)w;              w += (size_t)NEMB * SIXH * 4;       //   3.7 MB
    float* ps     = (float*)w;              w += (size_t)B * FIVEH * 4;         //   2.6 MB
    float* h      = (float*)w;              w += (size_t)B * H * 4;
    float* c      = (float*)w;              w += (size_t)B * H * 4;
    _Float16* hhi = (_Float16*)w;           w += (size_t)B * H * 2;
    _Float16* hlo = (_Float16*)w;           w += (size_t)B * H * 2;
    int* eidx     = (int*)w;                w += 512;
    _Float16* Xhi = (_Float16*)w;           w += (size_t)T * B * KTOT * 2;      //  16.8 MB
    _Float16* Xlo = (_Float16*)w;           w += (size_t)T * B * KTOT * 2;
    _Float16* WiThi = (_Float16*)w;         w += (size_t)SIXH * KTOT * 2;       //  25.2 MB
    _Float16* WiTlo = (_Float16*)w;         w += (size_t)SIXH * KTOT * 2;
    _Float16* WsThi = (_Float16*)w;         w += (size_t)FIVEH * H * 2;         //  10.5 MB
    _Float16* WsTlo = (_Float16*)w;         w += (size_t)FIVEH * H * 2;
    // WoT aliases Xhi (Xhi/Xlo dead after big_gemm; cvt_woT runs after big_gemm)
    float* WoT    = (float*)Xhi;

    float* dists = (float*)d_out;
    float* comms = dists + (size_t)T * B * C;

    init_kernel<<<512, 256, 0, stream>>>(h, c, hhi, hlo, eidx);
    cvt_x<<<(T * B * KTOT) / (256 * 4), 256, 0, stream>>>(X, Xhi, Xlo);
    cvt_wT<KTOT, SIXH><<<dim3(SIXH / 32, KTOT / 32), 256, 0, stream>>>(Wi, WiThi, WiTlo);
    cvt_wT<H, FIVEH><<<dim3(FIVEH / 32, H / 32), 256, 0, stream>>>(Ws, WsThi, WsTlo);
    etab_kernel<<<dim3(SIXH / 256, NEMB), 256, 0, stream>>>(embed, Wi, Etab);
    big_gemm_mfma<<<dim3(SIXH / 128, (T * B) / 128), 256, 0, stream>>>(Xhi, Xlo, WiThi, WiTlo, bi, P);
    cvt_woT<<<dim3(H / 256), 256, 0, stream>>>(Wo, WoT);   // after big_gemm: Xhi space reused

    void* args[] = {(void*)&P, (void*)&Etab, (void*)&bs, (void*)&WsThi, (void*)&WsTlo,
                    (void*)&hhi, (void*)&hlo, (void*)&ps, (void*)&WoT, (void*)&bo,
                    (void*)&labels, (void*)&dists, (void*)&comms};
    hipError_t err = hipLaunchCooperativeKernel((void*)fused_loop, dim3(NWG), dim3(256),
                                                args, 0, stream);
    if (err != hipSuccess) {
        // fallback: original per-timestep loop
        for (int t = 0; t < T; ++t) {
            ps_mfma<<<dim3(FIVEH / 64, B / 64), 256, 0, stream>>>(hhi, hlo, WsThi, WsTlo, ps);
            gate_kernel<<<dim3(H / 256, B), 256, 0, stream>>>(P, Etab, ps, bs, eidx, h, c, hhi, hlo, t);
            pred_kernel<<<B, 256, 0, stream>>>(h, Wo, bo, labels, dists, comms, eidx, t);
        }
    }
}

// Round 2
// 3061.925 us; speedup vs baseline: 1.0096x; 1.0096x over previous
//
#include <hip/hip_runtime.h>
#include <math.h>

#define H    1024
#define C    151
#define E    200
#define DIN  2048
#define T    32
#define B    128
#define SIXH  (6*H)   // 6144
#define FIVEH (5*H)   // 5120
#define KTOT  DIN     // 2048
#define NEMB  (C+1)   // 152
#define NWG   160     // persistent blocks; 160*32 = 5120 cols
#define COLS  32      // ps columns per WG

typedef _Float16 f16x8 __attribute__((ext_vector_type(8)));
typedef _Float16 f16x4 __attribute__((ext_vector_type(4)));
typedef float    f32x4 __attribute__((ext_vector_type(4)));

#define GLOAD_LDS16(g, l) __builtin_amdgcn_global_load_lds( \
    (const __attribute__((address_space(1))) unsigned int*)(g), \
    (__attribute__((address_space(3))) unsigned int*)(l), 16, 0, 0)

// ---- fast grid barrier: single counter + generation, agent-scope atomics ----
// cg::grid_group::sync() measured ~35us/sync at 160 WGs; this is ~2-3us.
__device__ __forceinline__ void gbar(int* cnt, int* gen) {
    __syncthreads();                       // drains this WG's stores (vmcnt 0) + wg sync
    if (threadIdx.x == 0) {
        int g = __hip_atomic_load(gen, __ATOMIC_RELAXED, __HIP_MEMORY_SCOPE_AGENT);
        if (__hip_atomic_fetch_add(cnt, 1, __ATOMIC_ACQ_REL, __HIP_MEMORY_SCOPE_AGENT) == NWG - 1) {
            __hip_atomic_store(cnt, 0, __ATOMIC_RELAXED, __HIP_MEMORY_SCOPE_AGENT);
            __hip_atomic_store(gen, g + 1, __ATOMIC_RELEASE, __HIP_MEMORY_SCOPE_AGENT);
        } else {
            while (__hip_atomic_load(gen, __ATOMIC_ACQUIRE, __HIP_MEMORY_SCOPE_AGENT) == g)
                __builtin_amdgcn_s_sleep(1);
        }
    }
    __syncthreads();
}

// ---------------- init: zero h, c, hhi, hlo, eidx, barrier ----------------
__global__ void init_kernel(float* h, float* c, _Float16* hhi, _Float16* hlo,
                            int* eidx, int* bar) {
    int i = blockIdx.x * blockDim.x + threadIdx.x;
    if (i < B * H) {
        h[i] = 0.f; c[i] = 0.f;
        hhi[i] = (_Float16)0.f; hlo[i] = (_Float16)0.f;
    }
    if (i < B) eidx[i] = 0;
    if (i < 2) bar[i] = 0;
}

// ---------------- X [4096][2048] fp32 -> hi/lo fp16 (same layout) ----------------
__global__ void cvt_x(const float* __restrict__ X, _Float16* __restrict__ hi,
                      _Float16* __restrict__ lo) {
    size_t i = ((size_t)blockIdx.x * 256 + threadIdx.x) * 4;
    float4 v = *(const float4*)(X + i);
    f16x4 h, l;
    h.x = (_Float16)v.x; l.x = (_Float16)(v.x - (float)h.x);
    h.y = (_Float16)v.y; l.y = (_Float16)(v.y - (float)h.y);
    h.z = (_Float16)v.z; l.z = (_Float16)(v.z - (float)h.z);
    h.w = (_Float16)v.w; l.w = (_Float16)(v.w - (float)h.w);
    *(f16x4*)(hi + i) = h;
    *(f16x4*)(lo + i) = l;
}

// ---------------- W [KR][NC] fp32 -> out [NC][KR] hi/lo fp16 (transposed) ----------------
template<int KR, int NC>
__global__ void cvt_wT(const float* __restrict__ W, _Float16* __restrict__ hi,
                       _Float16* __restrict__ lo) {
    __shared__ float tile[32][33];
    int n0 = blockIdx.x * 32, k0 = blockIdx.y * 32;
    int tx = threadIdx.x & 31, ty = threadIdx.x >> 5;   // ty 0..7
    #pragma unroll
    for (int i = 0; i < 4; ++i) {
        int k = ty + i * 8;
        tile[k][tx] = W[(size_t)(k0 + k) * NC + n0 + tx];
    }
    __syncthreads();
    #pragma unroll
    for (int i = 0; i < 4; ++i) {
        int n = ty + i * 8;
        float v = tile[tx][n];              // = W[k0+tx][n0+n]
        _Float16 h = (_Float16)v;
        size_t o = (size_t)(n0 + n) * KR + k0 + tx;
        hi[o] = h;
        lo[o] = (_Float16)(v - (float)h);
    }
}

// ---------------- Wo [H][C] fp32 -> WoT [C][H] ----------------
__global__ void cvt_woT(const float* __restrict__ Wo, float* __restrict__ WoT) {
    int k = blockIdx.x * 256 + threadIdx.x;  // 0..H-1
    for (int c = 0; c < C; ++c)
        WoT[(size_t)c * H + k] = Wo[(size_t)k * C + c];
}

// ---------------- Etab[k][n] = sum_e embed[k][e] * Wi[DIN+e][n]  (fp32) ----------------
__global__ void etab_kernel(const float* __restrict__ embed,
                            const float* __restrict__ Wi,
                            float* __restrict__ Etab) {
    int n = blockIdx.x * 256 + threadIdx.x;
    int k = blockIdx.y;
    const float* wp = Wi + (size_t)DIN * SIXH + n;
    const float* ep = embed + k * E;
    float acc = 0.f;
    #pragma unroll 8
    for (int e = 0; e < E; ++e)
        acc = fmaf(ep[e], wp[(size_t)e * SIXH], acc);
    Etab[(size_t)k * SIXH + n] = acc;
}

// ---------------- P = X @ Wi_x + bi, fp16x3 MFMA. tile 128x128, 4 waves x 64x64 ----------
// A = Xhi/Xlo [4096][2048] (k-contig). B = WiT hi/lo [6144][2048] (k-contig).
// LDS slot swizzle (T2 both-sides): source chunk kc ^ ((row>>1)&3), read slot lq ^ ((lr>>1)&3).
__global__ __launch_bounds__(256) void big_gemm_mfma(
    const _Float16* __restrict__ Ahi, const _Float16* __restrict__ Alo,
    const _Float16* __restrict__ Bhi, const _Float16* __restrict__ Blo,
    const float* __restrict__ bi, float* __restrict__ P)
{
    __shared__ __align__(16) _Float16 sAh[128 * 32];
    __shared__ __align__(16) _Float16 sAl[128 * 32];
    __shared__ __align__(16) _Float16 sBh[128 * 32];
    __shared__ __align__(16) _Float16 sBl[128 * 32];
    const int tid = threadIdx.x;
    const int n0 = blockIdx.x * 128;
    const int m0 = blockIdx.y * 128;
    const int lane = tid & 63, w = tid >> 6;
    const int wm = (w >> 1) * 64, wn = (w & 1) * 64;
    const int lr = lane & 15, lq = lane >> 4;

    f32x4 acc[4][4];
    #pragma unroll
    for (int i = 0; i < 4; ++i)
        #pragma unroll
        for (int j = 0; j < 4; ++j)
            acc[i][j] = (f32x4){0.f, 0.f, 0.f, 0.f};

    const int row0 = tid >> 2;        // 0..63
    const int kc = tid & 3;
    const int kcs = kc ^ ((row0 >> 1) & 3);   // swizzled source chunk
    const int sw = (lq ^ ((lr >> 1) & 3)) * 8; // swizzled read slot (halves)

    for (int k0 = 0; k0 < KTOT; k0 += 32) {
        #pragma unroll
        for (int i = 0; i < 2; ++i) {
            int row = row0 + i * 64;
            size_t ga = (size_t)(m0 + row) * KTOT + k0 + kcs * 8;
            size_t gb = (size_t)(n0 + row) * KTOT + k0 + kcs * 8;
            int loff = (i * 256 + tid) * 8;        // halves (linear dest)
            GLOAD_LDS16(Ahi + ga, sAh + loff);
            GLOAD_LDS16(Alo + ga, sAl + loff);
            GLOAD_LDS16(Bhi + gb, sBh + loff);
            GLOAD_LDS16(Blo + gb, sBl + loff);
        }
        __syncthreads();
        f16x8 ah[4], al[4], bh[4], bl[4];
        #pragma unroll
        for (int i = 0; i < 4; ++i) {
            ah[i] = *(const f16x8*)&sAh[(wm + i * 16 + lr) * 32 + sw];
            al[i] = *(const f16x8*)&sAl[(wm + i * 16 + lr) * 32 + sw];
            bh[i] = *(const f16x8*)&sBh[(wn + i * 16 + lr) * 32 + sw];
            bl[i] = *(const f16x8*)&sBl[(wn + i * 16 + lr) * 32 + sw];
        }
        #pragma unroll
        for (int i = 0; i < 4; ++i)
            #pragma unroll
            for (int j = 0; j < 4; ++j) {
                acc[i][j] = __builtin_amdgcn_mfma_f32_16x16x32_f16(ah[i], bh[j], acc[i][j], 0, 0, 0);
                acc[i][j] = __builtin_amdgcn_mfma_f32_16x16x32_f16(ah[i], bl[j], acc[i][j], 0, 0, 0);
                acc[i][j] = __builtin_amdgcn_mfma_f32_16x16x32_f16(al[i], bh[j], acc[i][j], 0, 0, 0);
            }
        __syncthreads();
    }
    #pragma unroll
    for (int i = 0; i < 4; ++i)
        #pragma unroll
        for (int j = 0; j < 4; ++j) {
            int gcol = n0 + wn + j * 16 + lr;
            float bv = bi[gcol];
            #pragma unroll
            for (int r = 0; r < 4; ++r) {
                int grow = m0 + wm + i * 16 + lq * 4 + r;
                P[(size_t)grow * SIXH + gcol] = acc[i][j][r] + bv;
            }
        }
}

// ================= persistent fused timestep loop (cooperative launch) =================
// Grid = NWG(160) x 256, 1 WG/CU (137KB LDS). Ws-slice resident in LDS, loaded ONCE.
// Per step: phase1 ps-slice + P/Etab reg-prefetch -> gbar -> phase2 gate+pred -> gbar.
__global__ __launch_bounds__(256, 1) void fused_loop(
    const float* __restrict__ P,
    const float* __restrict__ Etab,
    const float* __restrict__ bs,
    const _Float16* __restrict__ WsThi,
    const _Float16* __restrict__ WsTlo,
    _Float16* __restrict__ hhi,
    _Float16* __restrict__ hlo,
    float* __restrict__ ps,
    const float* __restrict__ WoT,
    const float* __restrict__ bo,
    const int* __restrict__ labels,
    float* __restrict__ dists,
    float* __restrict__ comms,
    int* bar)
{
    __shared__ __align__(16) _Float16 sBh[COLS * H];   // 64 KB, XOR-swizzled
    __shared__ __align__(16) _Float16 sBl[COLS * H];   // 64 KB
    __shared__ __align__(16) float hs[H];              // 4 KB (h_new row for pred)
    __shared__ float vals[256];
    __shared__ int   idxs[256];
    __shared__ int   s_eidx;

    const int wg  = blockIdx.x;
    const int tid = threadIdx.x;
    const int n0  = wg * COLS;
    const int lane = tid & 63, w = tid >> 6;
    const int lr = lane & 15, lq = lane >> 4;

    // ---- stage Ws slice into LDS, swizzled: granule byte ^= (col&7)<<4 ----
    for (int gi = tid; gi < COLS * (H / 8); gi += 256) {
        int col = gi >> 7;          // 128 granules of 16B per col
        int kg  = gi & 127;
        int dst = (col * (H * 2) + kg * 16) ^ ((col & 7) << 4);   // bytes
        *(f16x8*)((char*)sBh + dst) = *(const f16x8*)&WsThi[(size_t)(n0 + col) * H + kg * 8];
        *(f16x8*)((char*)sBl + dst) = *(const f16x8*)&WsTlo[(size_t)(n0 + col) * H + kg * 8];
    }

    float creg[4] = {0.f, 0.f, 0.f, 0.f};   // c-state, j = jj*256 + tid
    float bsr[4][5];
    if (wg < B) {
        #pragma unroll
        for (int jj = 0; jj < 4; ++jj)
            #pragma unroll
            for (int k = 0; k < 5; ++k)
                bsr[jj][k] = bs[k * H + jj * 256 + tid];
    }
    if (tid == 0) s_eidx = 0;
    __syncthreads();     // local staging done; cross-WG inputs are stream-ordered

    const int mrow0 = w * 32;

    for (int t = 0; t < T; ++t) {
        int eidx_cur = s_eidx;     // feedback embedding index for this step

        // ---------- phase 1: ps[:, n0:n0+32] = (h) @ Ws-slice, fp16x3 ----------
        f32x4 acc[2][2];
        #pragma unroll
        for (int i = 0; i < 2; ++i)
            #pragma unroll
            for (int j = 0; j < 2; ++j)
                acc[i][j] = (f32x4){0.f, 0.f, 0.f, 0.f};

        #pragma unroll 4
        for (int k0 = 0; k0 < H; k0 += 32) {
            f16x8 ah[2], al[2], bh[2], bl[2];
            #pragma unroll
            for (int i = 0; i < 2; ++i) {
                size_t ho = (size_t)(mrow0 + i * 16 + lr) * H + k0 + lq * 8;
                ah[i] = *(const f16x8*)&hhi[ho];
                al[i] = *(const f16x8*)&hlo[ho];
            }
            #pragma unroll
            for (int j = 0; j < 2; ++j) {
                int col = j * 16 + lr;
                int off = (col * (H * 2) + (k0 + lq * 8) * 2) ^ ((col & 7) << 4);
                bh[j] = *(const f16x8*)((const char*)sBh + off);
                bl[j] = *(const f16x8*)((const char*)sBl + off);
            }
            #pragma unroll
            for (int i = 0; i < 2; ++i)
                #pragma unroll
                for (int j = 0; j < 2; ++j) {
                    acc[i][j] = __builtin_amdgcn_mfma_f32_16x16x32_f16(ah[i], bh[j], acc[i][j], 0, 0, 0);
                    acc[i][j] = __builtin_amdgcn_mfma_f32_16x16x32_f16(ah[i], bl[j], acc[i][j], 0, 0, 0);
                    acc[i][j] = __builtin_amdgcn_mfma_f32_16x16x32_f16(al[i], bh[j], acc[i][j], 0, 0, 0);
                }
        }
        #pragma unroll
        for (int i = 0; i < 2; ++i)
            #pragma unroll
            for (int j = 0; j < 2; ++j)
                #pragma unroll
                for (int r = 0; r < 4; ++r)
                    ps[(size_t)(mrow0 + i * 16 + lq * 4 + r) * FIVEH + n0 + j * 16 + lr] = acc[i][j][r];

        // ---- T14 prefetch: P-row (cold HBM) + Etab-row into regs; latency hides
        // under barrier arrival/spin. Independent of ps/h, so legal pre-barrier. ----
        float pf[4][6], pe[4][6];
        if (wg < B) {
            const float* prow = P + (size_t)(t * B + wg) * SIXH;
            const float* erow = Etab + (size_t)eidx_cur * SIXH;
            #pragma unroll
            for (int jj = 0; jj < 4; ++jj)
                #pragma unroll
                for (int k = 0; k < 6; ++k) {
                    pf[jj][k] = prow[k * H + jj * 256 + tid];
                    pe[jj][k] = erow[k * H + jj * 256 + tid];
                }
        }

        gbar(bar, bar + 1);

        // ---------- phase 2: gate + pred + argmax for b = wg ----------
        if (wg < B) {
            const int b = wg;
            const float* psr = ps + (size_t)b * FIVEH;
            #pragma unroll
            for (int jj = 0; jj < 4; ++jj) {
                int j = jj * 256 + tid;
                float gv[5];
                #pragma unroll
                for (int k = 0; k < 5; ++k)
                    gv[k] = pf[jj][k] + pe[jj][k] + psr[k * H + j] + bsr[jj][k];
                float pi5 = pf[jj][5] + pe[jj][5];
                float ig = 1.f / (1.f + expf(-gv[0]));
                float fg = 1.f / (1.f + expf(-gv[1]));
                float mi = tanhf(gv[2]);
                float og = 1.f / (1.f + expf(-gv[3]));
                float hw = 1.f / (1.f + expf(-gv[4]));
                float cn = ig * mi + fg * creg[jj];
                float out = og * tanhf(cn);
                float hn = hw * out + (1.f - hw) * pi5;
                creg[jj] = cn;
                hs[j] = hn;
                _Float16 hh = (_Float16)hn;
                hhi[(size_t)b * H + j] = hh;
                hlo[(size_t)b * H + j] = (_Float16)(hn - (float)hh);
            }
            __syncthreads();
            float predv = 0.f;
            if (tid < C) {
                const float* wp = WoT + (size_t)tid * H;
                float a0 = bo[tid], a1 = 0.f, a2 = 0.f, a3 = 0.f;
                #pragma unroll 4
                for (int k = 0; k < H; k += 4) {
                    float4 w4 = *(const float4*)&wp[k];
                    float4 h4 = *(const float4*)&hs[k];
                    a0 = fmaf(h4.x, w4.x, a0);
                    a1 = fmaf(h4.y, w4.y, a1);
                    a2 = fmaf(h4.z, w4.z, a2);
                    a3 = fmaf(h4.w, w4.w, a3);
                }
                predv = (a0 + a1) + (a2 + a3);
                dists[(size_t)(t * B + b) * C + tid] = predv;
            }
            vals[tid] = (tid >= 1 && tid < C) ? predv : -1e30f;
            idxs[tid] = tid;
            __syncthreads();
            for (int s = 128; s > 0; s >>= 1) {
                if (tid < s) {
                    float v2 = vals[tid + s];
                    int   i2 = idxs[tid + s];
                    if (v2 > vals[tid] || (v2 == vals[tid] && i2 < idxs[tid])) {
                        vals[tid] = v2;
                        idxs[tid] = i2;
                    }
                }
                __syncthreads();
            }
            if (tid == 0) {
                int nzp = idxs[0];
                int lt = labels[t * B + b];
                int comm = (lt == 0) ? nzp : lt;
                comms[t * B + b] = (float)comm;
                s_eidx = comm + 1;
            }
        }
        gbar(bar, bar + 1);
    }
}

// ================= fallback per-timestep kernels (used only if coop launch fails) =====
__global__ __launch_bounds__(256) void ps_mfma(
    const _Float16* __restrict__ Ahi, const _Float16* __restrict__ Alo,
    const _Float16* __restrict__ Bhi, const _Float16* __restrict__ Blo,
    float* __restrict__ ps)
{
    __shared__ __align__(16) _Float16 sAh[64 * 32];
    __shared__ __align__(16) _Float16 sAl[64 * 32];
    __shared__ __align__(16) _Float16 sBh[64 * 32];
    __shared__ __align__(16) _Float16 sBl[64 * 32];
    const int tid = threadIdx.x;
    const int n0 = blockIdx.x * 64;
    const int m0 = blockIdx.y * 64;
    const int lane = tid & 63, w = tid >> 6;
    const int wm = (w >> 1) * 32, wn = (w & 1) * 32;
    const int lr = lane & 15, lq = lane >> 4;

    f32x4 acc[2][2];
    #pragma unroll
    for (int i = 0; i < 2; ++i)
        #pragma unroll
        for (int j = 0; j < 2; ++j)
            acc[i][j] = (f32x4){0.f, 0.f, 0.f, 0.f};

    const int row = tid >> 2;
    const int kc = tid & 3;

    for (int k0 = 0; k0 < H; k0 += 32) {
        size_t ga = (size_t)(m0 + row) * H + k0 + kc * 8;
        size_t gb = (size_t)(n0 + row) * H + k0 + kc * 8;
        int loff = tid * 8;
        GLOAD_LDS16(Ahi + ga, sAh + loff);
        GLOAD_LDS16(Alo + ga, sAl + loff);
        GLOAD_LDS16(Bhi + gb, sBh + loff);
        GLOAD_LDS16(Blo + gb, sBl + loff);
        __syncthreads();
        f16x8 ah[2], al[2], bh[2], bl[2];
        #pragma unroll
        for (int i = 0; i < 2; ++i) {
            ah[i] = *(const f16x8*)&sAh[(wm + i * 16 + lr) * 32 + lq * 8];
            al[i] = *(const f16x8*)&sAl[(wm + i * 16 + lr) * 32 + lq * 8];
            bh[i] = *(const f16x8*)&sBh[(wn + i * 16 + lr) * 32 + lq * 8];
            bl[i] = *(const f16x8*)&sBl[(wn + i * 16 + lr) * 32 + lq * 8];
        }
        #pragma unroll
        for (int i = 0; i < 2; ++i)
            #pragma unroll
            for (int j = 0; j < 2; ++j) {
                acc[i][j] = __builtin_amdgcn_mfma_f32_16x16x32_f16(ah[i], bh[j], acc[i][j], 0, 0, 0);
                acc[i][j] = __builtin_amdgcn_mfma_f32_16x16x32_f16(ah[i], bl[j], acc[i][j], 0, 0, 0);
                acc[i][j] = __builtin_amdgcn_mfma_f32_16x16x32_f16(al[i], bh[j], acc[i][j], 0, 0, 0);
            }
        __syncthreads();
    }
    #pragma unroll
    for (int i = 0; i < 2; ++i)
        #pragma unroll
        for (int j = 0; j < 2; ++j) {
            int gcol = n0 + wn + j * 16 + lr;
            #pragma unroll
            for (int r = 0; r < 4; ++r) {
                int grow = m0 + wm + i * 16 + lq * 4 + r;
                ps[(size_t)grow * FIVEH + gcol] = acc[i][j][r];
            }
        }
}

__global__ void gate_kernel(const float* __restrict__ P,
                            const float* __restrict__ Etab,
                            const float* __restrict__ ps,
                            const float* __restrict__ bs,
                            const int* __restrict__ eidx,
                            float* __restrict__ h,
                            float* __restrict__ c,
                            _Float16* __restrict__ hhi,
                            _Float16* __restrict__ hlo,
                            int t) {
    int j = blockIdx.x * 256 + threadIdx.x;
    int b = blockIdx.y;
    const float* prow = P + (size_t)(t * B + b) * SIXH;
    const float* erow = Etab + (size_t)eidx[b] * SIXH;
    const float* psr  = ps + (size_t)b * FIVEH;
    float g[5];
    #pragma unroll
    for (int k = 0; k < 5; ++k) {
        int col = k * H + j;
        g[k] = prow[col] + erow[col] + psr[col] + bs[col];
    }
    float pi5 = prow[5 * H + j] + erow[5 * H + j];
    float ig = 1.f / (1.f + expf(-g[0]));
    float fg = 1.f / (1.f + expf(-g[1]));
    float mi = tanhf(g[2]);
    float og = 1.f / (1.f + expf(-g[3]));
    float hw = 1.f / (1.f + expf(-g[4]));
    float cv = c[b * H + j];
    float cn = ig * mi + fg * cv;
    float out = og * tanhf(cn);
    float hn = hw * out + (1.f - hw) * pi5;
    c[b * H + j] = cn;
    h[b * H + j] = hn;
    _Float16 hh = (_Float16)hn;
    hhi[b * H + j] = hh;
    hlo[b * H + j] = (_Float16)(hn - (float)hh);
}

__global__ void pred_kernel(const float* __restrict__ h,
                            const float* __restrict__ Wo,
                            const float* __restrict__ bo,
                            const int* __restrict__ labels,
                            float* __restrict__ dists,
                            float* __restrict__ comms,
                            int* __restrict__ eidx,
                            int t) {
    __shared__ float hsb[H];
    __shared__ float vals[256];
    __shared__ int   idxs[256];
    int tid = threadIdx.x;
    int b = blockIdx.x;
    for (int i = tid; i < H / 4; i += 256)
        *(float4*)&hsb[i * 4] = *(const float4*)&h[b * H + i * 4];
    __syncthreads();
    float pred = 0.f;
    if (tid < C) {
        pred = bo[tid];
        #pragma unroll 8
        for (int k = 0; k < H; ++k)
            pred = fmaf(hsb[k], Wo[k * C + tid], pred);
        dists[(size_t)(t * B + b) * C + tid] = pred;
    }
    vals[tid] = (tid >= 1 && tid < C) ? pred : -1e30f;
    idxs[tid] = tid;
    __syncthreads();
    for (int s = 128; s > 0; s >>= 1) {
        if (tid < s) {
            float v2 = vals[tid + s];
            int   i2 = idxs[tid + s];
            if (v2 > vals[tid] || (v2 == vals[tid] && i2 < idxs[tid])) {
                vals[tid] = v2;
                idxs[tid] = i2;
            }
        }
        __syncthreads();
    }
    if (tid == 0) {
        int nzp = idxs[0];
        int lt = labels[t * B + b];
        int comm = (lt == 0) ? nzp : lt;
        comms[t * B + b] = (float)comm;
        eidx[b] = comm + 1;
    }
}

extern "C" void kernel_launch(void* const* d_in, const int* in_sizes, int n_in,
                              void* d_out, int out_size, void* d_ws, size_t ws_size,
                              hipStream_t stream) {
    const float* X      = (const float*)d_in[0];
    const int*   labels = (const int*)  d_in[1];
    const float* embed  = (const float*)d_in[2];
    const float* Wi     = (const float*)d_in[3];
    const float* bi     = (const float*)d_in[4];
    const float* Ws     = (const float*)d_in[5];
    const float* bs     = (const float*)d_in[6];
    const float* Wo     = (const float*)d_in[7];
    const float* bo     = (const float*)d_in[8];

    char* w = (char*)d_ws;
    float* P      = (float*)w;              w += (size_t)T * B * SIXH * 4;      // 100.7 MB
    float* Etab   = (float*)w;              w += (size_t)NEMB * SIXH * 4;       //   3.7 MB
    float* ps     = (float*)w;              w += (size_t)B * FIVEH * 4;         //   2.6 MB
    float* h      = (float*)w;              w += (size_t)B * H * 4;
    float* c      = (float*)w;              w += (size_t)B * H * 4;
    _Float16* hhi = (_Float16*)w;           w += (size_t)B * H * 2;
    _Float16* hlo = (_Float16*)w;           w += (size_t)B * H * 2;
    int* eidx     = (int*)w;                w += 512;
    int* bar      = (int*)w;                w += 512;
    _Float16* Xhi = (_Float16*)w;           w += (size_t)T * B * KTOT * 2;      //  16.8 MB
    _Float16* Xlo = (_Float16*)w;           w += (size_t)T * B * KTOT * 2;
    _Float16* WiThi = (_Float16*)w;         w += (size_t)SIXH * KTOT * 2;       //  25.2 MB
    _Float16* WiTlo = (_Float16*)w;         w += (size_t)SIXH * KTOT * 2;
    _Float16* WsThi = (_Float16*)w;         w += (size_t)FIVEH * H * 2;         //  10.5 MB
    _Float16* WsTlo = (_Float16*)w;         w += (size_t)FIVEH * H * 2;
    // WoT aliases Xhi (Xhi/Xlo dead after big_gemm; cvt_woT runs after big_gemm)
    float* WoT    = (float*)Xhi;

    float* dists = (float*)d_out;
    float* comms = dists + (size_t)T * B * C;

    init_kernel<<<512, 256, 0, stream>>>(h, c, hhi, hlo, eidx, bar);
    cvt_x<<<(T * B * KTOT) / (256 * 4), 256, 0, stream>>>(X, Xhi, Xlo);
    cvt_wT<KTOT, SIXH><<<dim3(SIXH / 32, KTOT / 32), 256, 0, stream>>>(Wi, WiThi, WiTlo);
    cvt_wT<H, FIVEH><<<dim3(FIVEH / 32, H / 32), 256, 0, stream>>>(Ws, WsThi, WsTlo);
    etab_kernel<<<dim3(SIXH / 256, NEMB), 256, 0, stream>>>(embed, Wi, Etab);
    big_gemm_mfma<<<dim3(SIXH / 128, (T * B) / 128), 256, 0, stream>>>(Xhi, Xlo, WiThi, WiTlo, bi, P);
    cvt_woT<<<dim3(H / 256), 256, 0, stream>>>(Wo, WoT);   // after big_gemm: Xhi space reused

    void* args[] = {(void*)&P, (void*)&Etab, (void*)&bs, (void*)&WsThi, (void*)&WsTlo,
                    (void*)&hhi, (void*)&hlo, (void*)&ps, (void*)&WoT, (void*)&bo,
                    (void*)&labels, (void*)&dists, (void*)&comms, (void*)&bar};
    hipError_t err = hipLaunchCooperativeKernel((void*)fused_loop, dim3(NWG), dim3(256),
                                                args, 0, stream);
    if (err != hipSuccess) {
        // fallback: original per-timestep loop
        for (int t = 0; t < T; ++t) {
            ps_mfma<<<dim3(FIVEH / 64, B / 64), 256, 0, stream>>>(hhi, hlo, WsThi, WsTlo, ps);
            gate_kernel<<<dim3(H / 256, B), 256, 0, stream>>>(P, Etab, ps, bs, eidx, h, c, hhi, hlo, t);
            pred_kernel<<<B, 256, 0, stream>>>(h, Wo, bo, labels, dists, comms, eidx, t);
        }
    }
}

// Round 3
// 2433.568 us; speedup vs baseline: 1.2702x; 1.2582x over previous
//
#include <hip/hip_runtime.h>
#include <math.h>

#define H    1024
#define C    151
#define E    200
#define DIN  2048
#define T    32
#define B    128
#define SIXH  (6*H)   // 6144
#define FIVEH (5*H)   // 5120
#define KTOT  DIN     // 2048
#define NEMB  (C+1)   // 152
#define NWG   160     // persistent blocks; 160*32 = 5120 cols
#define COLS  32      // ps columns per WG

typedef _Float16 f16x8 __attribute__((ext_vector_type(8)));
typedef _Float16 f16x4 __attribute__((ext_vector_type(4)));
typedef float    f32x4 __attribute__((ext_vector_type(4)));

#define GLOAD_LDS16(g, l) __builtin_amdgcn_global_load_lds( \
    (const __attribute__((address_space(1))) unsigned int*)(g), \
    (__attribute__((address_space(3))) unsigned int*)(l), 16, 0, 0)

// ---- flag-array grid barrier: per-WG padded slot, monotonic generation ----
// R1/R2 post-mortem: ANY single-counter barrier (cg's or ours) costs ~35us at
// 160 WGs because 160 device-scope RMWs on ONE line serialize cross-XCD.
// Here: arrival = uncontended fetch_add on own 64B slot (160 parallel lines);
// wait = relaxed polls of all slots (tid<NWG, one slot each) + syncthreads_and;
// one acquire fence at exit. No reset (monotonic val) -> no reset race.
__device__ __forceinline__ void gbar(int* slots, int tid, int val) {
    __syncthreads();   // WG stores drained (per-wave vmcnt) before release RMW
    if (tid == 0)
        __hip_atomic_fetch_add(&slots[blockIdx.x * 16], 1,
                               __ATOMIC_ACQ_REL, __HIP_MEMORY_SCOPE_AGENT);
    int ok;
    do {
        int v = val;
        if (tid < NWG)
            v = __hip_atomic_load(&slots[tid * 16],
                                  __ATOMIC_RELAXED, __HIP_MEMORY_SCOPE_AGENT);
        ok = __syncthreads_and(v >= val);
        if (!ok) __builtin_amdgcn_s_sleep(1);
    } while (!ok);
    __builtin_amdgcn_fence(__ATOMIC_ACQUIRE, "agent");
}

// ---------------- init: zero h, c, hhi, hlo, eidx, barrier slots ----------------
__global__ void init_kernel(float* h, float* c, _Float16* hhi, _Float16* hlo,
                            int* eidx, int* bar) {
    int i = blockIdx.x * blockDim.x + threadIdx.x;
    if (i < B * H) {
        h[i] = 0.f; c[i] = 0.f;
        hhi[i] = (_Float16)0.f; hlo[i] = (_Float16)0.f;
    }
    if (i < B) eidx[i] = 0;
    if (i < NWG * 16) bar[i] = 0;
}

// ---------------- X [4096][2048] fp32 -> hi/lo fp16 (same layout) ----------------
__global__ void cvt_x(const float* __restrict__ X, _Float16* __restrict__ hi,
                      _Float16* __restrict__ lo) {
    size_t i = ((size_t)blockIdx.x * 256 + threadIdx.x) * 4;
    float4 v = *(const float4*)(X + i);
    f16x4 h, l;
    h.x = (_Float16)v.x; l.x = (_Float16)(v.x - (float)h.x);
    h.y = (_Float16)v.y; l.y = (_Float16)(v.y - (float)h.y);
    h.z = (_Float16)v.z; l.z = (_Float16)(v.z - (float)h.z);
    h.w = (_Float16)v.w; l.w = (_Float16)(v.w - (float)h.w);
    *(f16x4*)(hi + i) = h;
    *(f16x4*)(lo + i) = l;
}

// ---------------- W [KR][NC] fp32 -> out [NC][KR] hi/lo fp16 (transposed) ----------------
template<int KR, int NC>
__global__ void cvt_wT(const float* __restrict__ W, _Float16* __restrict__ hi,
                       _Float16* __restrict__ lo) {
    __shared__ float tile[32][33];
    int n0 = blockIdx.x * 32, k0 = blockIdx.y * 32;
    int tx = threadIdx.x & 31, ty = threadIdx.x >> 5;   // ty 0..7
    #pragma unroll
    for (int i = 0; i < 4; ++i) {
        int k = ty + i * 8;
        tile[k][tx] = W[(size_t)(k0 + k) * NC + n0 + tx];
    }
    __syncthreads();
    #pragma unroll
    for (int i = 0; i < 4; ++i) {
        int n = ty + i * 8;
        float v = tile[tx][n];              // = W[k0+tx][n0+n]
        _Float16 h = (_Float16)v;
        size_t o = (size_t)(n0 + n) * KR + k0 + tx;
        hi[o] = h;
        lo[o] = (_Float16)(v - (float)h);
    }
}

// ---------------- Wo [H][C] fp32 -> WoT [C][H] ----------------
__global__ void cvt_woT(const float* __restrict__ Wo, float* __restrict__ WoT) {
    int k = blockIdx.x * 256 + threadIdx.x;  // 0..H-1
    for (int c = 0; c < C; ++c)
        WoT[(size_t)c * H + k] = Wo[(size_t)k * C + c];
}

// ---------------- Etab[k][n] = sum_e embed[k][e] * Wi[DIN+e][n]  (fp32) ----------------
__global__ void etab_kernel(const float* __restrict__ embed,
                            const float* __restrict__ Wi,
                            float* __restrict__ Etab) {
    int n = blockIdx.x * 256 + threadIdx.x;
    int k = blockIdx.y;
    const float* wp = Wi + (size_t)DIN * SIXH + n;
    const float* ep = embed + k * E;
    float acc = 0.f;
    #pragma unroll 8
    for (int e = 0; e < E; ++e)
        acc = fmaf(ep[e], wp[(size_t)e * SIXH], acc);
    Etab[(size_t)k * SIXH + n] = acc;
}

// ---------------- P = X @ Wi_x + bi, fp16x3 MFMA. tile 128x128, 4 waves x 64x64 ----------
__global__ __launch_bounds__(256) void big_gemm_mfma(
    const _Float16* __restrict__ Ahi, const _Float16* __restrict__ Alo,
    const _Float16* __restrict__ Bhi, const _Float16* __restrict__ Blo,
    const float* __restrict__ bi, float* __restrict__ P)
{
    __shared__ __align__(16) _Float16 sAh[128 * 32];
    __shared__ __align__(16) _Float16 sAl[128 * 32];
    __shared__ __align__(16) _Float16 sBh[128 * 32];
    __shared__ __align__(16) _Float16 sBl[128 * 32];
    const int tid = threadIdx.x;
    const int n0 = blockIdx.x * 128;
    const int m0 = blockIdx.y * 128;
    const int lane = tid & 63, w = tid >> 6;
    const int wm = (w >> 1) * 64, wn = (w & 1) * 64;
    const int lr = lane & 15, lq = lane >> 4;

    f32x4 acc[4][4];
    #pragma unroll
    for (int i = 0; i < 4; ++i)
        #pragma unroll
        for (int j = 0; j < 4; ++j)
            acc[i][j] = (f32x4){0.f, 0.f, 0.f, 0.f};

    const int row0 = tid >> 2;        // 0..63
    const int kc = tid & 3;
    const int kcs = kc ^ ((row0 >> 1) & 3);   // swizzled source chunk
    const int sw = (lq ^ ((lr >> 1) & 3)) * 8; // swizzled read slot (halves)

    for (int k0 = 0; k0 < KTOT; k0 += 32) {
        #pragma unroll
        for (int i = 0; i < 2; ++i) {
            int row = row0 + i * 64;
            size_t ga = (size_t)(m0 + row) * KTOT + k0 + kcs * 8;
            size_t gb = (size_t)(n0 + row) * KTOT + k0 + kcs * 8;
            int loff = (i * 256 + tid) * 8;        // halves (linear dest)
            GLOAD_LDS16(Ahi + ga, sAh + loff);
            GLOAD_LDS16(Alo + ga, sAl + loff);
            GLOAD_LDS16(Bhi + gb, sBh + loff);
            GLOAD_LDS16(Blo + gb, sBl + loff);
        }
        __syncthreads();
        f16x8 ah[4], al[4], bh[4], bl[4];
        #pragma unroll
        for (int i = 0; i < 4; ++i) {
            ah[i] = *(const f16x8*)&sAh[(wm + i * 16 + lr) * 32 + sw];
            al[i] = *(const f16x8*)&sAl[(wm + i * 16 + lr) * 32 + sw];
            bh[i] = *(const f16x8*)&sBh[(wn + i * 16 + lr) * 32 + sw];
            bl[i] = *(const f16x8*)&sBl[(wn + i * 16 + lr) * 32 + sw];
        }
        #pragma unroll
        for (int i = 0; i < 4; ++i)
            #pragma unroll
            for (int j = 0; j < 4; ++j) {
                acc[i][j] = __builtin_amdgcn_mfma_f32_16x16x32_f16(ah[i], bh[j], acc[i][j], 0, 0, 0);
                acc[i][j] = __builtin_amdgcn_mfma_f32_16x16x32_f16(ah[i], bl[j], acc[i][j], 0, 0, 0);
                acc[i][j] = __builtin_amdgcn_mfma_f32_16x16x32_f16(al[i], bh[j], acc[i][j], 0, 0, 0);
            }
        __syncthreads();
    }
    #pragma unroll
    for (int i = 0; i < 4; ++i)
        #pragma unroll
        for (int j = 0; j < 4; ++j) {
            int gcol = n0 + wn + j * 16 + lr;
            float bv = bi[gcol];
            #pragma unroll
            for (int r = 0; r < 4; ++r) {
                int grow = m0 + wm + i * 16 + lq * 4 + r;
                P[(size_t)grow * SIXH + gcol] = acc[i][j][r] + bv;
            }
        }
}

// ================= persistent fused timestep loop (cooperative launch) =================
__global__ __launch_bounds__(256, 1) void fused_loop(
    const float* __restrict__ P,
    const float* __restrict__ Etab,
    const float* __restrict__ bs,
    const _Float16* __restrict__ WsThi,
    const _Float16* __restrict__ WsTlo,
    _Float16* __restrict__ hhi,
    _Float16* __restrict__ hlo,
    float* __restrict__ ps,
    const float* __restrict__ WoT,
    const float* __restrict__ bo,
    const int* __restrict__ labels,
    float* __restrict__ dists,
    float* __restrict__ comms,
    int* bar)
{
    __shared__ __align__(16) _Float16 sBh[COLS * H];   // 64 KB, XOR-swizzled
    __shared__ __align__(16) _Float16 sBl[COLS * H];   // 64 KB
    __shared__ __align__(16) float hs[H];              // 4 KB (h_new row for pred)
    __shared__ float vals[256];
    __shared__ int   idxs[256];
    __shared__ int   s_eidx;

    const int wg  = blockIdx.x;
    const int tid = threadIdx.x;
    const int n0  = wg * COLS;
    const int lane = tid & 63, w = tid >> 6;
    const int lr = lane & 15, lq = lane >> 4;

    // ---- stage Ws slice into LDS, swizzled: granule byte ^= (col&7)<<4 ----
    for (int gi = tid; gi < COLS * (H / 8); gi += 256) {
        int col = gi >> 7;          // 128 granules of 16B per col
        int kg  = gi & 127;
        int dst = (col * (H * 2) + kg * 16) ^ ((col & 7) << 4);   // bytes
        *(f16x8*)((char*)sBh + dst) = *(const f16x8*)&WsThi[(size_t)(n0 + col) * H + kg * 8];
        *(f16x8*)((char*)sBl + dst) = *(const f16x8*)&WsTlo[(size_t)(n0 + col) * H + kg * 8];
    }

    float creg[4] = {0.f, 0.f, 0.f, 0.f};   // c-state, j = jj*256 + tid
    float bsr[4][5];
    if (wg < B) {
        #pragma unroll
        for (int jj = 0; jj < 4; ++jj)
            #pragma unroll
            for (int k = 0; k < 5; ++k)
                bsr[jj][k] = bs[k * H + jj * 256 + tid];
    }
    if (tid == 0) s_eidx = 0;
    __syncthreads();     // local staging done; cross-WG inputs are stream-ordered

    const int mrow0 = w * 32;
    int bval = 0;

    for (int t = 0; t < T; ++t) {
        int eidx_cur = s_eidx;     // feedback embedding index for this step

        // ---------- phase 1: ps[:, n0:n0+32] = (h) @ Ws-slice, fp16x3 ----------
        f32x4 acc[2][2];
        #pragma unroll
        for (int i = 0; i < 2; ++i)
            #pragma unroll
            for (int j = 0; j < 2; ++j)
                acc[i][j] = (f32x4){0.f, 0.f, 0.f, 0.f};

        #pragma unroll 4
        for (int k0 = 0; k0 < H; k0 += 32) {
            f16x8 ah[2], al[2], bh[2], bl[2];
            #pragma unroll
            for (int i = 0; i < 2; ++i) {
                size_t ho = (size_t)(mrow0 + i * 16 + lr) * H + k0 + lq * 8;
                ah[i] = *(const f16x8*)&hhi[ho];
                al[i] = *(const f16x8*)&hlo[ho];
            }
            #pragma unroll
            for (int j = 0; j < 2; ++j) {
                int col = j * 16 + lr;
                int off = (col * (H * 2) + (k0 + lq * 8) * 2) ^ ((col & 7) << 4);
                bh[j] = *(const f16x8*)((const char*)sBh + off);
                bl[j] = *(const f16x8*)((const char*)sBl + off);
            }
            #pragma unroll
            for (int i = 0; i < 2; ++i)
                #pragma unroll
                for (int j = 0; j < 2; ++j) {
                    acc[i][j] = __builtin_amdgcn_mfma_f32_16x16x32_f16(ah[i], bh[j], acc[i][j], 0, 0, 0);
                    acc[i][j] = __builtin_amdgcn_mfma_f32_16x16x32_f16(ah[i], bl[j], acc[i][j], 0, 0, 0);
                    acc[i][j] = __builtin_amdgcn_mfma_f32_16x16x32_f16(al[i], bh[j], acc[i][j], 0, 0, 0);
                }
        }
        #pragma unroll
        for (int i = 0; i < 2; ++i)
            #pragma unroll
            for (int j = 0; j < 2; ++j)
                #pragma unroll
                for (int r = 0; r < 4; ++r)
                    ps[(size_t)(mrow0 + i * 16 + lq * 4 + r) * FIVEH + n0 + j * 16 + lr] = acc[i][j][r];

        // ---- T14 prefetch: P-row (cold HBM) + Etab-row into regs; latency hides
        // under barrier arrival/poll. Independent of ps/h, so legal pre-barrier. ----
        float pf[4][6], pe[4][6];
        if (wg < B) {
            const float* prow = P + (size_t)(t * B + wg) * SIXH;
            const float* erow = Etab + (size_t)eidx_cur * SIXH;
            #pragma unroll
            for (int jj = 0; jj < 4; ++jj)
                #pragma unroll
                for (int k = 0; k < 6; ++k) {
                    pf[jj][k] = prow[k * H + jj * 256 + tid];
                    pe[jj][k] = erow[k * H + jj * 256 + tid];
                }
        }

        ++bval; gbar(bar, tid, bval);

        // ---------- phase 2: gate + pred + argmax for b = wg ----------
        if (wg < B) {
            const int b = wg;
            const float* psr = ps + (size_t)b * FIVEH;
            #pragma unroll
            for (int jj = 0; jj < 4; ++jj) {
                int j = jj * 256 + tid;
                float gv[5];
                #pragma unroll
                for (int k = 0; k < 5; ++k)
                    gv[k] = pf[jj][k] + pe[jj][k] + psr[k * H + j] + bsr[jj][k];
                float pi5 = pf[jj][5] + pe[jj][5];
                float ig = 1.f / (1.f + expf(-gv[0]));
                float fg = 1.f / (1.f + expf(-gv[1]));
                float mi = tanhf(gv[2]);
                float og = 1.f / (1.f + expf(-gv[3]));
                float hw = 1.f / (1.f + expf(-gv[4]));
                float cn = ig * mi + fg * creg[jj];
                float out = og * tanhf(cn);
                float hn = hw * out + (1.f - hw) * pi5;
                creg[jj] = cn;
                hs[j] = hn;
                _Float16 hh = (_Float16)hn;
                hhi[(size_t)b * H + j] = hh;
                hlo[(size_t)b * H + j] = (_Float16)(hn - (float)hh);
            }
            __syncthreads();
            float predv = 0.f;
            if (tid < C) {
                const float* wp = WoT + (size_t)tid * H;
                float a0 = bo[tid], a1 = 0.f, a2 = 0.f, a3 = 0.f;
                #pragma unroll 4
                for (int k = 0; k < H; k += 4) {
                    float4 w4 = *(const float4*)&wp[k];
                    float4 h4 = *(const float4*)&hs[k];
                    a0 = fmaf(h4.x, w4.x, a0);
                    a1 = fmaf(h4.y, w4.y, a1);
                    a2 = fmaf(h4.z, w4.z, a2);
                    a3 = fmaf(h4.w, w4.w, a3);
                }
                predv = (a0 + a1) + (a2 + a3);
                dists[(size_t)(t * B + b) * C + tid] = predv;
            }
            vals[tid] = (tid >= 1 && tid < C) ? predv : -1e30f;
            idxs[tid] = tid;
            __syncthreads();
            for (int s = 128; s > 0; s >>= 1) {
                if (tid < s) {
                    float v2 = vals[tid + s];
                    int   i2 = idxs[tid + s];
                    if (v2 > vals[tid] || (v2 == vals[tid] && i2 < idxs[tid])) {
                        vals[tid] = v2;
                        idxs[tid] = i2;
                    }
                }
                __syncthreads();
            }
            if (tid == 0) {
                int nzp = idxs[0];
                int lt = labels[t * B + b];
                int comm = (lt == 0) ? nzp : lt;
                comms[t * B + b] = (float)comm;
                s_eidx = comm + 1;
            }
        }
        ++bval; gbar(bar, tid, bval);
    }
}

// ================= fallback per-timestep kernels (used only if coop launch fails) =====
__global__ __launch_bounds__(256) void ps_mfma(
    const _Float16* __restrict__ Ahi, const _Float16* __restrict__ Alo,
    const _Float16* __restrict__ Bhi, const _Float16* __restrict__ Blo,
    float* __restrict__ ps)
{
    __shared__ __align__(16) _Float16 sAh[64 * 32];
    __shared__ __align__(16) _Float16 sAl[64 * 32];
    __shared__ __align__(16) _Float16 sBh[64 * 32];
    __shared__ __align__(16) _Float16 sBl[64 * 32];
    const int tid = threadIdx.x;
    const int n0 = blockIdx.x * 64;
    const int m0 = blockIdx.y * 64;
    const int lane = tid & 63, w = tid >> 6;
    const int wm = (w >> 1) * 32, wn = (w & 1) * 32;
    const int lr = lane & 15, lq = lane >> 4;

    f32x4 acc[2][2];
    #pragma unroll
    for (int i = 0; i < 2; ++i)
        #pragma unroll
        for (int j = 0; j < 2; ++j)
            acc[i][j] = (f32x4){0.f, 0.f, 0.f, 0.f};

    const int row = tid >> 2;
    const int kc = tid & 3;

    for (int k0 = 0; k0 < H; k0 += 32) {
        size_t ga = (size_t)(m0 + row) * H + k0 + kc * 8;
        size_t gb = (size_t)(n0 + row) * H + k0 + kc * 8;
        int loff = tid * 8;
        GLOAD_LDS16(Ahi + ga, sAh + loff);
        GLOAD_LDS16(Alo + ga, sAl + loff);
        GLOAD_LDS16(Bhi + gb, sBh + loff);
        GLOAD_LDS16(Blo + gb, sBl + loff);
        __syncthreads();
        f16x8 ah[2], al[2], bh[2], bl[2];
        #pragma unroll
        for (int i = 0; i < 2; ++i) {
            ah[i] = *(const f16x8*)&sAh[(wm + i * 16 + lr) * 32 + lq * 8];
            al[i] = *(const f16x8*)&sAl[(wm + i * 16 + lr) * 32 + lq * 8];
            bh[i] = *(const f16x8*)&sBh[(wn + i * 16 + lr) * 32 + lq * 8];
            bl[i] = *(const f16x8*)&sBl[(wn + i * 16 + lr) * 32 + lq * 8];
        }
        #pragma unroll
        for (int i = 0; i < 2; ++i)
            #pragma unroll
            for (int j = 0; j < 2; ++j) {
                acc[i][j] = __builtin_amdgcn_mfma_f32_16x16x32_f16(ah[i], bh[j], acc[i][j], 0, 0, 0);
                acc[i][j] = __builtin_amdgcn_mfma_f32_16x16x32_f16(ah[i], bl[j], acc[i][j], 0, 0, 0);
                acc[i][j] = __builtin_amdgcn_mfma_f32_16x16x32_f16(al[i], bh[j], acc[i][j], 0, 0, 0);
            }
        __syncthreads();
    }
    #pragma unroll
    for (int i = 0; i < 2; ++i)
        #pragma unroll
        for (int j = 0; j < 2; ++j) {
            int gcol = n0 + wn + j * 16 + lr;
            #pragma unroll
            for (int r = 0; r < 4; ++r) {
                int grow = m0 + wm + i * 16 + lq * 4 + r;
                ps[(size_t)grow * FIVEH + gcol] = acc[i][j][r];
            }
        }
}

__global__ void gate_kernel(const float* __restrict__ P,
                            const float* __restrict__ Etab,
                            const float* __restrict__ ps,
                            const float* __restrict__ bs,
                            const int* __restrict__ eidx,
                            float* __restrict__ h,
                            float* __restrict__ c,
                            _Float16* __restrict__ hhi,
                            _Float16* __restrict__ hlo,
                            int t) {
    int j = blockIdx.x * 256 + threadIdx.x;
    int b = blockIdx.y;
    const float* prow = P + (size_t)(t * B + b) * SIXH;
    const float* erow = Etab + (size_t)eidx[b] * SIXH;
    const float* psr  = ps + (size_t)b * FIVEH;
    float g[5];
    #pragma unroll
    for (int k = 0; k < 5; ++k) {
        int col = k * H + j;
        g[k] = prow[col] + erow[col] + psr[col] + bs[col];
    }
    float pi5 = prow[5 * H + j] + erow[5 * H + j];
    float ig = 1.f / (1.f + expf(-g[0]));
    float fg = 1.f / (1.f + expf(-g[1]));
    float mi = tanhf(g[2]);
    float og = 1.f / (1.f + expf(-g[3]));
    float hw = 1.f / (1.f + expf(-g[4]));
    float cv = c[b * H + j];
    float cn = ig * mi + fg * cv;
    float out = og * tanhf(cn);
    float hn = hw * out + (1.f - hw) * pi5;
    c[b * H + j] = cn;
    h[b * H + j] = hn;
    _Float16 hh = (_Float16)hn;
    hhi[b * H + j] = hh;
    hlo[b * H + j] = (_Float16)(hn - (float)hh);
}

__global__ void pred_kernel(const float* __restrict__ h,
                            const float* __restrict__ Wo,
                            const float* __restrict__ bo,
                            const int* __restrict__ labels,
                            float* __restrict__ dists,
                            float* __restrict__ comms,
                            int* __restrict__ eidx,
                            int t) {
    __shared__ float hsb[H];
    __shared__ float vals[256];
    __shared__ int   idxs[256];
    int tid = threadIdx.x;
    int b = blockIdx.x;
    for (int i = tid; i < H / 4; i += 256)
        *(float4*)&hsb[i * 4] = *(const float4*)&h[b * H + i * 4];
    __syncthreads();
    float pred = 0.f;
    if (tid < C) {
        pred = bo[tid];
        #pragma unroll 8
        for (int k = 0; k < H; ++k)
            pred = fmaf(hsb[k], Wo[k * C + tid], pred);
        dists[(size_t)(t * B + b) * C + tid] = pred;
    }
    vals[tid] = (tid >= 1 && tid < C) ? pred : -1e30f;
    idxs[tid] = tid;
    __syncthreads();
    for (int s = 128; s > 0; s >>= 1) {
        if (tid < s) {
            float v2 = vals[tid + s];
            int   i2 = idxs[tid + s];
            if (v2 > vals[tid] || (v2 == vals[tid] && i2 < idxs[tid])) {
                vals[tid] = v2;
                idxs[tid] = i2;
            }
        }
        __syncthreads();
    }
    if (tid == 0) {
        int nzp = idxs[0];
        int lt = labels[t * B + b];
        int comm = (lt == 0) ? nzp : lt;
        comms[t * B + b] = (float)comm;
        eidx[b] = comm + 1;
    }
}

extern "C" void kernel_launch(void* const* d_in, const int* in_sizes, int n_in,
                              void* d_out, int out_size, void* d_ws, size_t ws_size,
                              hipStream_t stream) {
    const float* X      = (const float*)d_in[0];
    const int*   labels = (const int*)  d_in[1];
    const float* embed  = (const float*)d_in[2];
    const float* Wi     = (const float*)d_in[3];
    const float* bi     = (const float*)d_in[4];
    const float* Ws     = (const float*)d_in[5];
    const float* bs     = (const float*)d_in[6];
    const float* Wo     = (const float*)d_in[7];
    const float* bo     = (const float*)d_in[8];

    char* w = (char*)d_ws;
    float* P      = (float*)w;              w += (size_t)T * B * SIXH * 4;      // 100.7 MB
    float* Etab   = (float*)w;              w += (size_t)NEMB * SIXH * 4;       //   3.7 MB
    float* ps     = (float*)w;              w += (size_t)B * FIVEH * 4;         //   2.6 MB
    float* h      = (float*)w;              w += (size_t)B * H * 4;
    float* c      = (float*)w;              w += (size_t)B * H * 4;
    _Float16* hhi = (_Float16*)w;           w += (size_t)B * H * 2;
    _Float16* hlo = (_Float16*)w;           w += (size_t)B * H * 2;
    int* eidx     = (int*)w;                w += 512;
    int* bar      = (int*)w;                w += 16384;                          // NWG*16 ints padded
    _Float16* Xhi = (_Float16*)w;           w += (size_t)T * B * KTOT * 2;      //  16.8 MB
    _Float16* Xlo = (_Float16*)w;           w += (size_t)T * B * KTOT * 2;
    _Float16* WiThi = (_Float16*)w;         w += (size_t)SIXH * KTOT * 2;       //  25.2 MB
    _Float16* WiTlo = (_Float16*)w;         w += (size_t)SIXH * KTOT * 2;
    _Float16* WsThi = (_Float16*)w;         w += (size_t)FIVEH * H * 2;         //  10.5 MB
    _Float16* WsTlo = (_Float16*)w;         w += (size_t)FIVEH * H * 2;
    // WoT aliases Xhi (Xhi/Xlo dead after big_gemm; cvt_woT runs after big_gemm)
    float* WoT    = (float*)Xhi;

    float* dists = (float*)d_out;
    float* comms = dists + (size_t)T * B * C;

    init_kernel<<<512, 256, 0, stream>>>(h, c, hhi, hlo, eidx, bar);
    cvt_x<<<(T * B * KTOT) / (256 * 4), 256, 0, stream>>>(X, Xhi, Xlo);
    cvt_wT<KTOT, SIXH><<<dim3(SIXH / 32, KTOT / 32), 256, 0, stream>>>(Wi, WiThi, WiTlo);
    cvt_wT<H, FIVEH><<<dim3(FIVEH / 32, H / 32), 256, 0, stream>>>(Ws, WsThi, WsTlo);
    etab_kernel<<<dim3(SIXH / 256, NEMB), 256, 0, stream>>>(embed, Wi, Etab);
    big_gemm_mfma<<<dim3(SIXH / 128, (T * B) / 128), 256, 0, stream>>>(Xhi, Xlo, WiThi, WiTlo, bi, P);
    cvt_woT<<<dim3(H / 256), 256, 0, stream>>>(Wo, WoT);   // after big_gemm: Xhi space reused

    void* args[] = {(void*)&P, (void*)&Etab, (void*)&bs, (void*)&WsThi, (void*)&WsTlo,
                    (void*)&hhi, (void*)&hlo, (void*)&ps, (void*)&WoT, (void*)&bo,
                    (void*)&labels, (void*)&dists, (void*)&comms, (void*)&bar};
    hipError_t err = hipLaunchCooperativeKernel((void*)fused_loop, dim3(NWG), dim3(256),
                                                args, 0, stream);
    if (err != hipSuccess) {
        // fallback: original per-timestep loop
        for (int t = 0; t < T; ++t) {
            ps_mfma<<<dim3(FIVEH / 64, B / 64), 256, 0, stream>>>(hhi, hlo, WsThi, WsTlo, ps);
            gate_kernel<<<dim3(H / 256, B), 256, 0, stream>>>(P, Etab, ps, bs, eidx, h, c, hhi, hlo, t);
            pred_kernel<<<B, 256, 0, stream>>>(h, Wo, bo, labels, dists, comms, eidx, t);
        }
    }
}